// Round 7
// baseline (134.188 us; speedup 1.0000x reference)
//
#include <hip/hip_runtime.h>

// out = conv2d(poly(img), W, stride=1, pad=1) / 27, poly(v) = A0 + A1*v + A2*v^2
// (identity-kernel branch contributes exactly zero; 1/27 folded into poly).
// Implicit GEMM on bf16 MFMA: A = weights (M=o), B = poly(img) (N = spatial x),
// K = (ky,kx,c) = 576, mfma_f32_32x32x16_bf16.
//
// R11: counted-vmcnt pipeline (T3/T4). R10 proved __syncthreads() (vmcnt(0)
// drain) makes ping-pong useless; this round uses raw s_barrier + counted
// s_waitcnt so DMA stays in flight ACROSS barriers, transform, and MFMA.
//  - All loop vmem = global_load_lds with wave-uniform unconditional counts:
//    image quarter-chunks (4ch, 12 KB, 2 loads/wave, y-clamped + dup-padded)
//    and per-chunk weight slabs (18 KB -> LDS, 3 loads/wave). MFMA phase reads
//    A and B from LDS only -> zero vmem there -> no compiler-forced drains.
//  - Queue enumeration gives K(q) = (q&3)==1 ? 3 : 0: each wait retires exactly
//    the quarter being transformed; next quarter + weight slab stay in flight.
//  - LDS: slots 2x12288 + stag 24960 + wlds 18432 = 67968 B, 2 blocks/CU.
//  - Epilogue: direct full-line global stores from acc (R9, verified).

typedef __bf16 bf16;
typedef __attribute__((ext_vector_type(4))) __bf16 bf16x4;
typedef __attribute__((ext_vector_type(8))) __bf16 bf16x8;
typedef __attribute__((ext_vector_type(16))) float f32x16;

static constexpr float A0 = -0.000287f / 27.0f;
static constexpr float A1 =  0.266f    / 27.0f;
static constexpr float A2 = -0.1097f   / 27.0f;

#define NN 16
#define CI 64
#define HH 128
#define WW 128
#define OO 64
#define LDS_BYTES 67968   // 24576 slots + 24960 stag + 18432 wlds

// Repack weights [O][C][3][3] fp32 -> [chunk 4][slice 9][o 64][c16 16] bf16
// (c16 = channel within chunk; LDS-linear per-chunk slabs of 9216 elements).
__global__ void repack_w(const float* __restrict__ w, bf16* __restrict__ wrb) {
    int idx = blockIdx.x * 256 + threadIdx.x;        // 4*9*64*16 = 36864
    if (idx >= 36864) return;
    int c16 = idx & 15;
    int o   = (idx >> 4) & 63;
    int sc  = idx >> 10;            // 0..35 = chunk*9 + slice
    int ch  = sc / 9;
    int s   = sc - ch * 9;
    int ky = s / 3, kx = s - ky * 3;
    int c = ch * 16 + c16;
    wrb[idx] = (bf16)w[((o * CI + c) * 3 + ky) * 3 + kx];
}

__global__ __launch_bounds__(512, 4) void conv_mfma(const float* __restrict__ img,
                                                    const bf16* __restrict__ wrb,
                                                    float* __restrict__ out) {
    // slots: 2 x [unit 12][1 KB] f32 (quarter-chunk: 6 rows x 4 ch x 512 B)
    // stag:  [row 12][xp 130][cj 8] bf16 = 24960 B (MFMA B staging)
    // wlds:  [slice 9][o 64][c16 16] bf16 = 18432 B (MFMA A, current chunk)
    extern __shared__ __align__(16) char smem[];
    float* slots = (float*)smem;                       // slot s at s*3072 floats
    bf16*  ilds  = (bf16*)(smem + 24576);
    bf16*  wlds  = (bf16*)(smem + 49536);

    const int tid = threadIdx.x;
    const int b   = blockIdx.x;
    const int y0  = (b & 31) * 4;
    const int n   = b >> 5;

    const int wv   = tid >> 6;
    const int lane = tid & 63;
    const int lm   = lane & 31;      // A: o-row / B: x-col / C: col
    const int half = lane >> 5;      // k-half selector
    const int yl   = wv >> 1;
    const int Xh   = (wv & 1) * 64;

    // Image DMA, quarter q (4 channels). 12 units of 1 KB; unit u = r*2+cp covers
    // row r, channels {2cp, 2cp+1}: lane l -> ch 2cp+(l>>5), x 4*(l&31).
    // EXACTLY 2 loads per wave, unconditional (y clamped; waves 4-7 dup their
    // unit — same data, same dest, benign). Counted-vmcnt requires uniformity.
    auto idma = [&](int q) {
        float* slot = slots + (q & 1) * 3072;
        const int cbase = (q >> 2) * 16 + (q & 3) * 4;
        #pragma unroll
        for (int k = 0; k < 2; ++k) {
            const int u  = (k == 0) ? wv : (wv < 4 ? 8 + wv : wv);
            const int r  = u >> 1;
            const int cp = u & 1;
            int yi = y0 - 1 + r;
            yi = yi < 0 ? 0 : (yi > 127 ? 127 : yi);   // clamp: load garbage, zeroed later
            const float* g = img + ((n * CI + cbase + 2 * cp + (lane >> 5)) * HH + yi) * WW
                           + 4 * (lane & 31);
            __builtin_amdgcn_global_load_lds(
                (const __attribute__((address_space(1))) void*)g,
                (__attribute__((address_space(3))) void*)(slot + u * 256),
                16, 0, 0);
        }
    };

    // Weight DMA, chunk c: 18 units of 1 KB, linear copy wrb[c] -> wlds.
    // EXACTLY 3 loads per wave (waves 2-7 dup unit wv).
    auto wdma = [&](int c) {
        #pragma unroll
        for (int k = 0; k < 3; ++k) {
            const int u = (k == 0) ? wv : (k == 1 ? 8 + wv : (wv < 2 ? 16 + wv : wv));
            const bf16* g = wrb + c * 9216 + u * 512 + lane * 8;
            __builtin_amdgcn_global_load_lds(
                (const __attribute__((address_space(1))) void*)g,
                (__attribute__((address_space(3))) void*)(wlds + u * 512),
                16, 0, 0);
        }
    };

    // Transform quarter q: poly(slot[q&1]) -> stag rows r*2 + ((q&3)>>1),
    // cj range [4*(q&1), +4). 390 items (r 6 x xh 65), one per thread.
    auto transform = [&](int q) {
        const float* slot = slots + (q & 1) * 3072;
        const int ccl = (q & 3) >> 1;          // cc8 row selector
        const int cj4 = (q & 1) * 4;           // cj offset within row
        if (tid < 390) {
            const int r  = tid / 65;
            const int xh = tid - r * 65;
            const int yi = y0 - 1 + r;
            bf16* rowp = ilds + (r * 2 + ccl) * (130 * 8) + cj4;
            if (xh < 64) {
                bf16x4 pk0, pk1;
                if ((unsigned)yi < 128u) {
                    #pragma unroll
                    for (int j = 0; j < 4; ++j) {
                        float2 v = *(const float2*)(slot + (r * 2 + (j >> 1)) * 256
                                                    + (j & 1) * 128 + 2 * xh);
                        pk0[j] = (bf16)(A0 + v.x * (A1 + A2 * v.x));
                        pk1[j] = (bf16)(A0 + v.y * (A1 + A2 * v.y));
                    }
                } else {
                    #pragma unroll
                    for (int j = 0; j < 4; ++j) { pk0[j] = (bf16)0.0f; pk1[j] = (bf16)0.0f; }
                }
                *(bf16x4*)(rowp + (2 * xh + 1) * 8) = pk0;
                *(bf16x4*)(rowp + (2 * xh + 2) * 8) = pk1;
            } else {
                bf16x4 z;
                #pragma unroll
                for (int j = 0; j < 4; ++j) z[j] = (bf16)0.0f;
                *(bf16x4*)(rowp + 0) = z;            // xp=0   (xi=-1, conv pad)
                *(bf16x4*)(rowp + 129 * 8) = z;      // xp=129 (xi=128, conv pad)
            }
        }
    };

    f32x16 acc[2][2];
    #pragma unroll
    for (int i = 0; i < 2; ++i)
        #pragma unroll
        for (int j = 0; j < 2; ++j)
            #pragma unroll
            for (int k = 0; k < 16; ++k) acc[i][j][k] = 0.0f;

    idma(0);

    // Per-wave vmem queue (oldest first) at each wait:
    //   q==0       : [idma0(2)]                  -> vmcnt(0)
    //   q%4==1     : [idma_q(2)][wdma_c(3)]      -> vmcnt(3)  (weights keep flying)
    //   q%4==2     : [wdma_c(3)][idma_q(2)]      -> vmcnt(0)  (wlds ready for MFMA)
    //   q%4==3, 0  : [idma_q(2)]                 -> vmcnt(0)
    for (int q = 0; q < 16; ++q) {
        if ((q & 3) == 1) asm volatile("s_waitcnt vmcnt(3)" ::: "memory");
        else              asm volatile("s_waitcnt vmcnt(0)" ::: "memory");
        __builtin_amdgcn_sched_barrier(0);
        __builtin_amdgcn_s_barrier();       // idma(q) visible everywhere; prior
        __builtin_amdgcn_sched_barrier(0);  // slot/wlds readers all done
        if (q < 15) idma(q + 1);            // into slot[!(q&1)]: in flight across
        if ((q & 3) == 0) wdma(q >> 2);     // transform+MFMA, never drained early
        transform(q);
        if ((q & 3) == 3) {
            asm volatile("s_waitcnt lgkmcnt(0)" ::: "memory");
            __builtin_amdgcn_sched_barrier(0);
            __builtin_amdgcn_s_barrier();   // stag complete everywhere
            __builtin_amdgcn_sched_barrier(0);
            const bf16x8* ifr = (const bf16x8*)ilds;
            #pragma unroll
            for (int ky = 0; ky < 3; ++ky) {
                const int r = yl + ky;
                #pragma unroll
                for (int kx = 0; kx < 3; ++kx) {
                    const int slice = ky * 3 + kx;
                    bf16x8 a0 = *(const bf16x8*)(wlds + (slice * 64 + lm) * 16 + half * 8);
                    bf16x8 a1 = *(const bf16x8*)(wlds + (slice * 64 + 32 + lm) * 16 + half * 8);
                    const int ib = (r * 2 + half) * 130 + Xh + lm + kx;   // b128, conflict-free
                    bf16x8 b0 = ifr[ib];
                    bf16x8 b1 = ifr[ib + 32];
                    acc[0][0] = __builtin_amdgcn_mfma_f32_32x32x16_bf16(a0, b0, acc[0][0], 0, 0, 0);
                    acc[0][1] = __builtin_amdgcn_mfma_f32_32x32x16_bf16(a0, b1, acc[0][1], 0, 0, 0);
                    acc[1][0] = __builtin_amdgcn_mfma_f32_32x32x16_bf16(a1, b0, acc[1][0], 0, 0, 0);
                    acc[1][1] = __builtin_amdgcn_mfma_f32_32x32x16_bf16(a1, b1, acc[1][1], 0, 0, 0);
                }
            }
        }
    }

    // ---- Epilogue: direct stores. Half-wave = 32 lanes x 4 B = one full
    // 128-B line per (o,y) segment; every output line written exactly once. ----
    // C/D layout: col = lane&31 (x), row-in-32 = (rg&3) + 8*(rg>>2) + 4*half (o).
    const int ybase = (n * OO * HH + (y0 + yl)) * WW;
    #pragma unroll
    for (int p = 0; p < 2; ++p)
        #pragma unroll
        for (int xt = 0; xt < 2; ++xt) {
            const int x = Xh + xt * 32 + lm;
            #pragma unroll
            for (int rg = 0; rg < 16; ++rg) {
                const int o = (rg & 3) + 8 * (rg >> 2) + 4 * half + 32 * p;
                out[ybase + o * (HH * WW) + x] = acc[p][xt][rg];
            }
        }
}

extern "C" void kernel_launch(void* const* d_in, const int* in_sizes, int n_in,
                              void* d_out, int out_size, void* d_ws, size_t ws_size,
                              hipStream_t stream) {
    const float* img = (const float*)d_in[0];
    const float* w   = (const float*)d_in[1];
    // d_in[2] (identity_kernel) unused: its branch convolves exact zeros.
    float* out = (float*)d_out;
    bf16* wrb  = (bf16*)d_ws;    // 36864 bf16 = 73728 B repacked weights

    static bool attr_done = false;
    if (!attr_done) {
        (void)hipFuncSetAttribute((const void*)conv_mfma,
                                  hipFuncAttributeMaxDynamicSharedMemorySize, LDS_BYTES);
        attr_done = true;
    }

    repack_w<<<(36864 + 255) / 256, 256, 0, stream>>>(w, wrb);
    conv_mfma<<<NN * (HH / 4), 512, LDS_BYTES, stream>>>(img, wrb, out);
}

// Round 8
// 130.560 us; speedup vs baseline: 1.0278x; 1.0278x over previous
//
#include <hip/hip_runtime.h>

// out = conv2d(poly(img), W, stride=1, pad=1) / 27, poly(v) = A0 + A1*v + A2*v^2
// (identity-kernel branch contributes exactly zero; 1/27 folded into poly).
// Implicit GEMM on bf16 MFMA: A = weights (M=o), B = poly(img) (N = spatial x),
// K = (ky,kx,c) = 576, mfma_f32_32x32x16_bf16.
//
// R12: phase-diversity attack. R9/R10/R11 (three different intra-block schedules)
// all plateau at 44-46 µs with NO pipe saturated; per-CU resource times SUM
// (HBM 18 + LDS 14 + VALU 5 + MFMA 7 ~= 44) because 2 barrier-locked 8-wave
// blocks/CU give only 2 phase domains. Fix = more independent barrier groups:
//  - 256-thread blocks (4 waves), output 64o x 2y x 128x, grid 1024 -> 4
//    blocks/CU (LDS 33,280 B, <=128-reg tier). When one block barriers/stages,
//    three others MFMA/store.
//  - y-split (not x: R7 showed x-halo drags full cache lines). Reg-staged
//    (no raw-LDS round trip), weights from global (L1-hot, R4-proven).
//  - T1 XCD swizzle (1024%8==0, bijective): adjacent y-tiles -> same XCD L2,
//    absorbing the doubled halo re-reads.
//  - Direct full-line global stores from acc (R9-proven epilogue).

typedef __bf16 bf16;
typedef __attribute__((ext_vector_type(8))) __bf16 bf16x8;
typedef __attribute__((ext_vector_type(16))) float f32x16;

static constexpr float A0 = -0.000287f / 27.0f;
static constexpr float A1 =  0.266f    / 27.0f;
static constexpr float A2 = -0.1097f   / 27.0f;

#define NN 16
#define CI 64
#define HH 128
#define WW 128
#define OO 64

// Repack weights [O][C][3][3] fp32 -> [slice=ky*3+kx][cc8=c/8][o][cj=c%8] bf16.
__global__ void repack_w(const float* __restrict__ w, bf16* __restrict__ wrb) {
    int idx = blockIdx.x * 256 + threadIdx.x;        // 9*8*64*8 = 36864
    if (idx >= 36864) return;
    int cj    = idx & 7;
    int o     = (idx >> 3) & 63;
    int cc8   = (idx >> 9) & 7;
    int slice = idx >> 12;
    int ky = slice / 3, kx = slice - ky * 3;
    int c = cc8 * 8 + cj;
    wrb[idx] = (bf16)w[((o * CI + c) * 3 + ky) * 3 + kx];
}

__global__ __launch_bounds__(256, 4) void conv_mfma(const float* __restrict__ img,
                                                    const bf16* __restrict__ wrb,
                                                    float* __restrict__ out) {
    // stag[buf 2]: [r 4][ccl 2][xp 130][cj 8] bf16 = 16640 B each; 33280 total.
    __shared__ __align__(16) bf16 ilds[2][8320];

    const int tid  = threadIdx.x;
    const int braw = blockIdx.x;
    const int b    = (braw & 7) * 128 + (braw >> 3);   // XCD swizzle, bijective
    const int y0   = (b & 63) * 2;
    const int n    = b >> 6;

    const int wv   = tid >> 6;       // 0..3
    const int lane = tid & 63;
    const int lm   = lane & 31;      // A: o-row / B: x-col / C: col
    const int half = lane >> 5;      // k-half selector (which cc8 of the pair)
    const int yl   = wv >> 1;        // output row within tile (0..1)
    const int Xh   = (wv & 1) * 64;

    // Staging items: id = tid + 256*it, id -> (r = id>>7, ccl = (id>>6)&1,
    // xh = id&63). Item covers x = 2xh, 2xh+1 for 8 channels (float2 x 8).
    auto stage_load = [&](int chunk, int it, float2* v) {
        const int id = tid + (it << 8);
        const int r = id >> 7, ccl = (id >> 6) & 1, xh = id & 63;
        const int yi = y0 - 1 + r;
        if ((unsigned)yi < 128u) {
            const float* p = img + ((n * CI + chunk * 16 + ccl * 8) * HH + yi) * WW + 2 * xh;
            #pragma unroll
            for (int j = 0; j < 8; ++j) v[j] = *(const float2*)(p + j * HH * WW);
        }
    };
    auto stage_write = [&](int buf, int it, float2* v) {
        const int id = tid + (it << 8);
        const int r = id >> 7, ccl = (id >> 6) & 1, xh = id & 63;
        const int yi = y0 - 1 + r;
        bf16* rowp = &ilds[buf][(r * 2 + ccl) * (130 * 8)];
        bf16x8 pk0, pk1;
        if ((unsigned)yi < 128u) {
            #pragma unroll
            for (int j = 0; j < 8; ++j) {
                pk0[j] = (bf16)(A0 + v[j].x * (A1 + A2 * v[j].x));
                pk1[j] = (bf16)(A0 + v[j].y * (A1 + A2 * v[j].y));
            }
        } else {
            #pragma unroll
            for (int j = 0; j < 8; ++j) { pk0[j] = (bf16)0.0f; pk1[j] = (bf16)0.0f; }
        }
        *(bf16x8*)(rowp + (2 * xh + 1) * 8) = pk0;
        *(bf16x8*)(rowp + (2 * xh + 2) * 8) = pk1;
        if (it == 0 && tid < 8) {            // halo columns: r=tid>>1, ccl=tid&1
            bf16* hp = &ilds[buf][((tid >> 1) * 2 + (tid & 1)) * (130 * 8)];
            bf16x8 z;
            #pragma unroll
            for (int j = 0; j < 8; ++j) z[j] = (bf16)0.0f;
            *(bf16x8*)(hp + 0) = z;            // xp=0   (xi=-1, conv pad)
            *(bf16x8*)(hp + 129 * 8) = z;      // xp=129 (xi=128, conv pad)
        }
    };

    f32x16 acc[2][2];
    #pragma unroll
    for (int i = 0; i < 2; ++i)
        #pragma unroll
        for (int j = 0; j < 2; ++j)
            #pragma unroll
            for (int k = 0; k < 16; ++k) acc[i][j][k] = 0.0f;

    const bf16x8* wfr = (const bf16x8*)wrb;

    {   // prologue: chunk 0 into buf 0
        float2 v[8];
        stage_load(0, 0, v); stage_write(0, 0, v);
        stage_load(0, 1, v); stage_write(0, 1, v);
    }

    for (int chunk = 0; chunk < 4; ++chunk) {
        __syncthreads();                       // stag[chunk&1] staged & visible
        float2 v[8];
        if (chunk < 3) stage_load(chunk + 1, 0, v);   // T14: issue before MFMA
        const bf16x8* ifr = (const bf16x8*)ilds[chunk & 1];
        const int cc8g = chunk * 2 + half;
        #pragma unroll
        for (int ky = 0; ky < 3; ++ky) {
            const int r = yl + ky;             // input row 0..3
            #pragma unroll
            for (int kx = 0; kx < 3; ++kx) {
                const int slice = ky * 3 + kx;
                bf16x8 a0 = wfr[(slice * 8 + cc8g) * 64 + lm];        // weights, L1-hot
                bf16x8 a1 = wfr[(slice * 8 + cc8g) * 64 + 32 + lm];
                const int ib = (r * 2 + half) * 130 + Xh + lm + kx;   // conflict-free b128
                bf16x8 b0 = ifr[ib];
                bf16x8 b1 = ifr[ib + 32];
                acc[0][0] = __builtin_amdgcn_mfma_f32_32x32x16_bf16(a0, b0, acc[0][0], 0, 0, 0);
                acc[0][1] = __builtin_amdgcn_mfma_f32_32x32x16_bf16(a0, b1, acc[0][1], 0, 0, 0);
                acc[1][0] = __builtin_amdgcn_mfma_f32_32x32x16_bf16(a1, b0, acc[1][0], 0, 0, 0);
                acc[1][1] = __builtin_amdgcn_mfma_f32_32x32x16_bf16(a1, b1, acc[1][1], 0, 0, 0);
            }
        }
        if (chunk < 3) {
            const int nb = (chunk + 1) & 1;
            stage_write(nb, 0, v);                   // poly+write after compute
            stage_load(chunk + 1, 1, v);             // round 1 (TLP covers stall)
            stage_write(nb, 1, v);
        }
    }

    // ---- Epilogue: direct stores. Half-wave = 32 lanes x 4 B = one full
    // 128-B line per (o,y) segment; every output line written exactly once. ----
    // C/D layout: col = lane&31 (x), row-in-32 = (rg&3) + 8*(rg>>2) + 4*half (o).
    const int ybase = (n * OO * HH + (y0 + yl)) * WW;
    #pragma unroll
    for (int p = 0; p < 2; ++p)
        #pragma unroll
        for (int xt = 0; xt < 2; ++xt) {
            const int x = Xh + xt * 32 + lm;
            #pragma unroll
            for (int rg = 0; rg < 16; ++rg) {
                const int o = (rg & 3) + 8 * (rg >> 2) + 4 * half + 32 * p;
                out[ybase + o * (HH * WW) + x] = acc[p][xt][rg];
            }
        }
}

extern "C" void kernel_launch(void* const* d_in, const int* in_sizes, int n_in,
                              void* d_out, int out_size, void* d_ws, size_t ws_size,
                              hipStream_t stream) {
    const float* img = (const float*)d_in[0];
    const float* w   = (const float*)d_in[1];
    // d_in[2] (identity_kernel) unused: its branch convolves exact zeros.
    float* out = (float*)d_out;
    bf16* wrb  = (bf16*)d_ws;    // 36864 bf16 = 73728 B repacked weights

    repack_w<<<(36864 + 255) / 256, 256, 0, stream>>>(w, wrb);
    conv_mfma<<<NN * (HH / 2), 256, 0, stream>>>(img, wrb, out);
}